// Round 14
// baseline (341.963 us; speedup 1.0000x reference)
//
#include <hip/hip_runtime.h>

typedef unsigned short u16;
typedef unsigned int   u32;

#define SEQ 2048
#define EMB 2048
#define TD  6144

using bf16x8 = __attribute__((ext_vector_type(8))) __bf16;
using f32x4  = __attribute__((ext_vector_type(4))) float;
using u16x8v = __attribute__((ext_vector_type(8))) u16;

typedef __attribute__((address_space(1))) const void* gas_t;
typedef __attribute__((address_space(3))) void*       las_t;
#define GLOAD16(g, l) __builtin_amdgcn_global_load_lds((gas_t)(g), (las_t)(l), 16, 0, 0)

__device__ __forceinline__ u16 f2bf(float f) {
  u32 u = __float_as_uint(f);
  u += 0x7fffu + ((u >> 16) & 1u);   // round-to-nearest-even
  return (u16)(u >> 16);
}
__device__ __forceinline__ float bf2f(u16 b) {
  u32 u = (u32)b << 16;
  return __uint_as_float(u);
}

// -------- fused prep: cast x->xb (blocks 0..16383), cast+transpose W->Wt (rest) --------
__global__ __launch_bounds__(256) void prep_kern(const float* __restrict__ x,
                                                 u16* __restrict__ xb,
                                                 const float* __restrict__ W,
                                                 u16* __restrict__ Wt) {
  int bid = blockIdx.x;
  int tid = threadIdx.x;
  if (bid < 16384) {
    size_t i = ((size_t)bid * 256 + tid) * 4;
    float4 v = *(const float4*)(x + i);
    ushort4 u;
    u.x = f2bf(v.x); u.y = f2bf(v.y); u.z = f2bf(v.z); u.w = f2bf(v.w);
    *(ushort4*)(xb + i) = u;
  } else {
    __shared__ float t[64][65];
    int wb = bid - 16384;
    int c0 = (wb % 96) * 64, r0 = (wb / 96) * 64;
#pragma unroll
    for (int i = 0; i < 4; ++i) {
      int flat = i * 1024 + tid * 4;
      int r = flat >> 6, c = flat & 63;
      float4 v = *(const float4*)(W + (size_t)(r0 + r) * TD + c0 + c);
      t[r][c] = v.x; t[r][c + 1] = v.y; t[r][c + 2] = v.z; t[r][c + 3] = v.w;
    }
    __syncthreads();
#pragma unroll
    for (int i = 0; i < 4; ++i) {
      int flat = i * 1024 + tid * 4;
      int wr = flat >> 6, wc = flat & 63;
      ushort4 u;
      u.x = f2bf(t[wc + 0][wr]); u.y = f2bf(t[wc + 1][wr]);
      u.z = f2bf(t[wc + 2][wr]); u.w = f2bf(t[wc + 3][wr]);
      *(ushort4*)(Wt + (size_t)(c0 + wr) * EMB + r0 + wc) = u;
    }
  }
}

// ------------- qkv GEMM: 256x256 tile, 8 waves, 1-deep prefetch, 1 barrier/K-tile -------------
// R14: stage tile t+1 into NXT buffer (nobody reads it this tile) -> zero intra-tile
// barriers; waves skew freely so SIMD co-schedules one wave's MFMA with another's ds_reads
// (m114 TLP overlap) and the compiler pipelines reads under MFMAs with counted lgkm waits.
// Per tile: {8 stages, reads+MFMA p0..p3, vmcnt(0), s_barrier}. vmcnt(0) drains loads
// issued a full tile earlier (>=2500cy >> 900cy HBM) -> ~free.
// [qk | vT] = xb @ Wt^T + bias. col<4096 -> qk[8192][4096] bf16;
// col>=4096 -> vT[b][d][n] via in-LDS transpose. grid 768 x 512 thr.
__global__ __launch_bounds__(512, 2) void gemm_qkv(const u16* __restrict__ Ab,
                                                   const u16* __restrict__ Bb,
                                                   u16* __restrict__ Cb,
                                                   u16* __restrict__ Cb2,
                                                   const float* __restrict__ bias) {
  __shared__ char lds[2][65536];
  constexpr int lda = EMB, ldb = EMB;
  int bid = blockIdx.x;
  int wg = (bid & 7) * 96 + (bid >> 3);            // XCD swizzle
  const u16* A = Ab;
  const u16* Bt = Bb;
  int row0 = (wg / 24) * 256, col0 = (wg % 24) * 256, nk = EMB / 64;

  int tid = threadIdx.x;
  int wave = tid >> 6, lane = tid & 63;
  int wm = wave >> 2, wn = wave & 3;

  int sbase[8];
#pragma unroll
  for (int i = 0; i < 4; ++i) sbase[i] = 32768 + i * 8192 + wave * 1024;
#pragma unroll
  for (int i = 0; i < 4; ++i)
    sbase[4 + i] = i * 4096 + ((wave < 4) ? wave * 1024 : 16384 + (wave - 4) * 1024);

  auto stageb = [&](int bi, int t, int buf) {
    int ob = sbase[bi];
    int obl = ob + lane * 16;
    int row = (obl & 32767) >> 7;
    int cb = obl & 127;
    int c = ((cb ^ ((row & 7) << 4)) >> 1) + t * 64;
    const u16* src = (ob < 32768) ? (A + (size_t)(row0 + row) * lda + c)
                                  : (Bt + (size_t)(col0 + row) * ldb + c);
    GLOAD16(src, (char*)&lds[buf][0] + ob);
  };
  auto ldA = [&](int buf, int rr, int ks) -> bf16x8 {
    int cb = ks * 64 + (lane >> 4) * 16;
    return *(const bf16x8*)&lds[buf][rr * 128 + (cb ^ ((rr & 7) << 4))];
  };
  auto ldB = [&](int buf, int rr, int ks) -> bf16x8 {
    int cb = ks * 64 + (lane >> 4) * 16;
    return *(const bf16x8*)&lds[buf][32768 + rr * 128 + (cb ^ ((rr & 7) << 4))];
  };

  f32x4 acc[8][4];
#pragma unroll
  for (int m = 0; m < 8; ++m)
#pragma unroll
    for (int n = 0; n < 4; ++n) acc[m][n] = (f32x4){0.f, 0.f, 0.f, 0.f};

  // prologue: stage tile0 -> buf0
#pragma unroll
  for (int bi = 0; bi < 8; ++bi) stageb(bi, 0, 0);
  asm volatile("s_waitcnt vmcnt(0)" ::: "memory");
  __builtin_amdgcn_s_barrier();

  for (int t = 0; t < nk; ++t) {
    int cur = t & 1, nxt = cur ^ 1;
    bool pf = (t + 1 < nk);
    if (pf) {
#pragma unroll
      for (int bi = 0; bi < 8; ++bi) stageb(bi, t + 1, nxt);
    }
    bf16x8 bfg[4][2];
#pragma unroll
    for (int n = 0; n < 4; ++n)
#pragma unroll
      for (int ks = 0; ks < 2; ++ks)
        bfg[n][ks] = ldB(cur, wn * 64 + n * 16 + (lane & 15), ks);
#pragma unroll
    for (int p = 0; p < 4; ++p) {
      bf16x8 afg[2][2];
#pragma unroll
      for (int m = 0; m < 2; ++m)
#pragma unroll
        for (int ks = 0; ks < 2; ++ks)
          afg[m][ks] = ldA(cur, wm * 128 + (p * 2 + m) * 16 + (lane & 15), ks);
      __builtin_amdgcn_s_setprio(1);
#pragma unroll
      for (int m = 0; m < 2; ++m)
#pragma unroll
        for (int n = 0; n < 4; ++n)
#pragma unroll
          for (int ks = 0; ks < 2; ++ks)
            acc[p * 2 + m][n] = __builtin_amdgcn_mfma_f32_16x16x32_bf16(
                afg[m][ks], bfg[n][ks], acc[p * 2 + m][n], 0, 0, 0);
      __builtin_amdgcn_s_setprio(0);
    }
    if (pf) asm volatile("s_waitcnt vmcnt(0)" ::: "memory");
    __builtin_amdgcn_s_barrier();
  }

  int ln = lane & 15;
  int l4 = (lane >> 4) << 2;
  int rb = row0 + wm * 128, cb0 = col0 + wn * 64;
  if (col0 < 4096) {
    u16* C = Cb;
#pragma unroll
    for (int n = 0; n < 4; ++n) {
      float bv = bias[cb0 + n * 16 + ln];
#pragma unroll
      for (int m = 0; m < 8; ++m)
#pragma unroll
        for (int r = 0; r < 4; ++r)
          C[(size_t)(rb + m * 16 + l4 + r) * 4096 + cb0 + n * 16 + ln] =
              f2bf(acc[m][n][r] + bv);
    }
  } else {
    u16* vTb = Cb2 + (size_t)(row0 >> 11) * SEQ * SEQ;
    int nbase = row0 & 2047;
    u16 (*T)[264] = (u16(*)[264])(&lds[0][0]);   // lds[0] quiescent: last read t=nk-2
    int half = wn >> 1;
    int dloc0 = (wn & 1) * 64;
#pragma unroll
    for (int hh = 0; hh < 2; ++hh) {
      if (half == hh) {
#pragma unroll
        for (int n = 0; n < 4; ++n) {
          float bv = bias[cb0 + n * 16 + ln];
          int dl = dloc0 + n * 16 + ln;
#pragma unroll
          for (int m = 0; m < 8; ++m) {
            int nn = wm * 128 + m * 16 + l4;
#pragma unroll
            for (int r = 0; r < 4; ++r)
              T[dl][nn + r] = f2bf(acc[m][n][r] + bv);
          }
        }
      }
      __syncthreads();
      int dl = tid >> 5, nn = (tid & 31) * 8;
#pragma unroll
      for (int it = 0; it < 8; ++it) {
        int loc = it * 16 + dl;
        *(u16x8v*)&vTb[(size_t)(col0 - 4096 + hh * 128 + loc) * SEQ + nbase + nn] =
            *(const u16x8v*)&T[loc][nn];
      }
      __syncthreads();
    }
  }
}

// ------------- 128x128 NT GEMM, 4 waves, 1-deep prefetch, 1 barrier/K-tile -------------
// Same R14 structure as gemm_qkv: stage t+1 -> nxt, no intra-tile barriers.
// MODE 1: att = scale * q @ k^T -> bf16, row stride 4096 u16 (same layout as P). grid 544.
// MODE 2: y = P @ vT^T fp32, K=(qi+1)*128, qi-descending dispatch. grid 1024.
template <int MODE>
__global__ __launch_bounds__(256, 2) void gemm128(const u16* __restrict__ Ab,
                                                  const u16* __restrict__ Bb,
                                                  void* __restrict__ Cb) {
  __shared__ char lds[2][32768];
  constexpr int lda = 4096;
  constexpr int ldb = (MODE == 1) ? 4096 : SEQ;

  int bid = blockIdx.x;
  const u16 *A, *Bt;
  int row0, col0, nk;
  size_t coff;
  if constexpr (MODE == 1) {
    constexpr int CPX = 544 / 8;
    int wg = (bid & 7) * CPX + (bid >> 3);
    int b = wg / 136, tq = wg % 136;
    int qi = (int)((sqrtf(8.f * (float)tq + 1.f) - 1.f) * 0.5f);
    while ((qi + 1) * (qi + 2) / 2 <= tq) ++qi;
    while (qi * (qi + 1) / 2 > tq) --qi;
    int kj = tq - qi * (qi + 1) / 2;
    A = Ab + (size_t)b * SEQ * 4096;       // q slice
    Bt = A + 2048;                         // k slice
    row0 = qi * 128; col0 = kj * 128; nk = EMB / 64;
    coff = (size_t)b * SEQ * 4096;         // att bf16, stride 4096 u16
  } else {
    // qi-descending: heavy blocks dispatched first. 64 blocks per qi (8 per XCD).
    int xcd = bid & 7, idx = bid >> 3;     // idx 0..127
    int qi = 15 - (idx >> 3);
    int g = xcd * 8 + (idx & 7);           // 0..63
    int b = g >> 4, nj = g & 15;
    A = Ab + (size_t)b * SEQ * 4096;       // P, stride 4096
    Bt = Bb + (size_t)b * SEQ * SEQ;       // vT
    row0 = qi * 128; col0 = nj * 128; nk = (qi + 1) * 2;
    coff = (size_t)b * SEQ * SEQ;
  }

  int tid = threadIdx.x;
  int wave = tid >> 6, lane = tid & 63;
  int wm = wave >> 1, wn = wave & 1;       // 2x2 wave grid, 64x64 out each
  int ln = lane & 15;

  int sbase[8];
#pragma unroll
  for (int i = 0; i < 4; ++i) sbase[i] = 16384 + i * 4096 + wave * 1024;
#pragma unroll
  for (int i = 0; i < 4; ++i) sbase[4 + i] = i * 4096 + wave * 1024;

  auto stageb = [&](int bi, int t, int buf) {
    int ob = sbase[bi];
    int obl = ob + lane * 16;
    int row = (obl & 16383) >> 7;
    int cb = obl & 127;
    int c = ((cb ^ ((row & 7) << 4)) >> 1) + t * 64;
    const u16* src = (ob < 16384) ? (A + (size_t)(row0 + row) * lda + c)
                                  : (Bt + (size_t)(col0 + row) * ldb + c);
    GLOAD16(src, (char*)&lds[buf][0] + ob);
  };
  auto ldA = [&](int buf, int rr, int ks) -> bf16x8 {
    int cb = ks * 64 + (lane >> 4) * 16;
    return *(const bf16x8*)&lds[buf][rr * 128 + (cb ^ ((rr & 7) << 4))];
  };
  auto ldB = [&](int buf, int rr, int ks) -> bf16x8 {
    int cb = ks * 64 + (lane >> 4) * 16;
    return *(const bf16x8*)&lds[buf][16384 + rr * 128 + (cb ^ ((rr & 7) << 4))];
  };

  f32x4 acc[4][4];
#pragma unroll
  for (int m = 0; m < 4; ++m)
#pragma unroll
    for (int n = 0; n < 4; ++n) acc[m][n] = (f32x4){0.f, 0.f, 0.f, 0.f};

  // prologue: stage tile0 -> buf0
#pragma unroll
  for (int bi = 0; bi < 8; ++bi) stageb(bi, 0, 0);
  asm volatile("s_waitcnt vmcnt(0)" ::: "memory");
  __builtin_amdgcn_s_barrier();

  for (int t = 0; t < nk; ++t) {
    int cur = t & 1, nxt = cur ^ 1;
    bool pf = (t + 1 < nk);
    if (pf) {
#pragma unroll
      for (int bi = 0; bi < 8; ++bi) stageb(bi, t + 1, nxt);
    }
    bf16x8 bfg[4][2];
#pragma unroll
    for (int n = 0; n < 4; ++n)
#pragma unroll
      for (int ks = 0; ks < 2; ++ks)
        bfg[n][ks] = ldB(cur, wn * 64 + n * 16 + ln, ks);
#pragma unroll
    for (int p = 0; p < 2; ++p) {
      bf16x8 afg[2][2];
#pragma unroll
      for (int m = 0; m < 2; ++m)
#pragma unroll
        for (int ks = 0; ks < 2; ++ks)
          afg[m][ks] = ldA(cur, wm * 64 + (p * 2 + m) * 16 + ln, ks);
      __builtin_amdgcn_s_setprio(1);
#pragma unroll
      for (int m = 0; m < 2; ++m)
#pragma unroll
        for (int n = 0; n < 4; ++n)
#pragma unroll
          for (int ks = 0; ks < 2; ++ks)
            acc[p * 2 + m][n] = __builtin_amdgcn_mfma_f32_16x16x32_bf16(
                afg[m][ks], bfg[n][ks], acc[p * 2 + m][n], 0, 0, 0);
      __builtin_amdgcn_s_setprio(0);
    }
    if (pf) asm volatile("s_waitcnt vmcnt(0)" ::: "memory");
    __builtin_amdgcn_s_barrier();
  }

  int l4 = (lane >> 4) << 2;
  int rb = row0 + wm * 64, cb0 = col0 + wn * 64;
  if constexpr (MODE == 1) {
    // scaled bf16 att, row stride 4096 u16 (same layout softmax/gemm<2> use)
    u16* C = (u16*)Cb + coff;
    const float scale = 0.022097086912079608f;   // 1/sqrt(2048)
#pragma unroll
    for (int m = 0; m < 4; ++m)
#pragma unroll
      for (int n = 0; n < 4; ++n)
#pragma unroll
        for (int r = 0; r < 4; ++r)
          C[(size_t)(rb + m * 16 + l4 + r) * 4096 + cb0 + n * 16 + ln] =
              f2bf(acc[m][n][r] * scale);
  } else {
    float* C = (float*)Cb + coff;
#pragma unroll
    for (int m = 0; m < 4; ++m)
#pragma unroll
      for (int n = 0; n < 4; ++n)
#pragma unroll
        for (int r = 0; r < 4; ++r)
          C[(size_t)(rb + m * 16 + l4 + r) * SEQ + cb0 + n * 16 + ln] = acc[m][n][r];
  }
}

// ---------------- row softmax: att bf16 -> P bf16 (in place, stride 4096), denom ----------------
// 256 threads x 8 contiguous els (one ushort8 load/store). 128-granular extent; masked exp->0.
__global__ __launch_bounds__(256) void softmax_kern(u16* __restrict__ att,
                                                    float* __restrict__ denom) {
  int row = blockIdx.x;          // b*SEQ + q
  int q = row & (SEQ - 1);
  u16* arow = att + (size_t)row * 4096;
  int jlen = ((q >> 7) + 1) << 7;          // 128-tile-aligned row extent
  int tid = threadIdx.x;
  int j0 = tid * 8;
  float NI = -__builtin_inff();
  float a[8];
#pragma unroll
  for (int e = 0; e < 8; ++e) a[e] = NI;
  if (j0 < jlen) {
    u16x8v v = *(const u16x8v*)(arow + j0);
#pragma unroll
    for (int e = 0; e < 8; ++e)
      a[e] = (j0 + e <= q) ? bf2f(v[e]) : NI;
  }
  float mx = a[0];
#pragma unroll
  for (int e = 1; e < 8; ++e) mx = fmaxf(mx, a[e]);
#pragma unroll
  for (int off = 32; off; off >>= 1) mx = fmaxf(mx, __shfl_xor(mx, off, 64));
  __shared__ float red[8];
  int wv = tid >> 6;
  if ((tid & 63) == 0) red[wv] = mx;
  __syncthreads();
  mx = fmaxf(fmaxf(red[0], red[1]), fmaxf(red[2], red[3]));
  float s = 0.f;
#pragma unroll
  for (int e = 0; e < 8; ++e) { a[e] = expf(a[e] - mx); s += a[e]; }
#pragma unroll
  for (int off = 32; off; off >>= 1) s += __shfl_xor(s, off, 64);
  if ((tid & 63) == 0) red[4 + wv] = s;
  __syncthreads();                          // fences all arow reads before P writes
  s = red[4] + red[5] + red[6] + red[7];
  float inv = 1.0f / s;
  if (j0 < jlen) {
    u16x8v u;
#pragma unroll
    for (int e = 0; e < 8; ++e) u[e] = f2bf(a[e] * inv);
    *(u16x8v*)(arow + j0) = u;
  }
  if (tid == 0) denom[row] = s;
}

extern "C" void kernel_launch(void* const* d_in, const int* in_sizes, int n_in,
                              void* d_out, int out_size, void* d_ws, size_t ws_size,
                              hipStream_t stream) {
  const float* x    = (const float*)d_in[0];
  const float* W    = (const float*)d_in[1];
  const float* bias = (const float*)d_in[2];

  // ws layout (201,326,592 B):
  //  [0,         67108864)  qk bf16 [8192][4096] (q cols 0..2047, k cols 2048..4095)
  //  [67108864, 100663296)  vT bf16 [4][2048][2048]   (written by gemm_qkv epilogue)
  //  [100663296,134217728)  xb bf16 [8192][2048]      (dead after gemm_qkv)
  //  [134217728,201326592)  phase1: Wt bf16 (first 25MB, dead after gemm_qkv)
  //                         phase2: att bf16 / P bf16 in-place [8192 rows][4096 u16]
  if (ws_size < 201326592u) return;

  char* w = (char*)d_ws;
  u16*   qk  = (u16*)w;
  u16*   vT  = (u16*)(w + 67108864);
  u16*   xb  = (u16*)(w + 100663296);
  u16*   Wt  = (u16*)(w + 134217728);
  u16*   att = (u16*)(w + 134217728);      // bf16, row stride 4096 u16; P in place

  float* y     = (float*)d_out;
  float* denom = y + (size_t)4 * SEQ * SEQ;

  prep_kern<<<19456, 256, 0, stream>>>(x, xb, W, Wt);
  gemm_qkv<<<768, 512, 0, stream>>>(xb, Wt, qk, vT, bias);
  gemm128<1><<<544, 256, 0, stream>>>(qk, nullptr, att);
  softmax_kern<<<8192, 256, 0, stream>>>(att, denom);
  gemm128<2><<<1024, 256, 0, stream>>>(att, vT, y);
}

// Round 15
// 326.519 us; speedup vs baseline: 1.0473x; 1.0473x over previous
//
#include <hip/hip_runtime.h>

typedef unsigned short u16;
typedef unsigned int   u32;

#define SEQ 2048
#define EMB 2048
#define TD  6144

using bf16x8 = __attribute__((ext_vector_type(8))) __bf16;
using f32x4  = __attribute__((ext_vector_type(4))) float;
using u16x8v = __attribute__((ext_vector_type(8))) u16;

typedef __attribute__((address_space(1))) const void* gas_t;
typedef __attribute__((address_space(3))) void*       las_t;
#define GLOAD16(g, l) __builtin_amdgcn_global_load_lds((gas_t)(g), (las_t)(l), 16, 0, 0)

__device__ __forceinline__ u16 f2bf(float f) {
  u32 u = __float_as_uint(f);
  u += 0x7fffu + ((u >> 16) & 1u);   // round-to-nearest-even
  return (u16)(u >> 16);
}
__device__ __forceinline__ float bf2f(u16 b) {
  u32 u = (u32)b << 16;
  return __uint_as_float(u);
}

// -------- fused prep: cast x->xb (blocks 0..16383), cast+transpose W->Wt (rest) --------
__global__ __launch_bounds__(256) void prep_kern(const float* __restrict__ x,
                                                 u16* __restrict__ xb,
                                                 const float* __restrict__ W,
                                                 u16* __restrict__ Wt) {
  int bid = blockIdx.x;
  int tid = threadIdx.x;
  if (bid < 16384) {
    size_t i = ((size_t)bid * 256 + tid) * 4;
    float4 v = *(const float4*)(x + i);
    ushort4 u;
    u.x = f2bf(v.x); u.y = f2bf(v.y); u.z = f2bf(v.z); u.w = f2bf(v.w);
    *(ushort4*)(xb + i) = u;
  } else {
    __shared__ float t[64][65];
    int wb = bid - 16384;
    int c0 = (wb % 96) * 64, r0 = (wb / 96) * 64;
#pragma unroll
    for (int i = 0; i < 4; ++i) {
      int flat = i * 1024 + tid * 4;
      int r = flat >> 6, c = flat & 63;
      float4 v = *(const float4*)(W + (size_t)(r0 + r) * TD + c0 + c);
      t[r][c] = v.x; t[r][c + 1] = v.y; t[r][c + 2] = v.z; t[r][c + 3] = v.w;
    }
    __syncthreads();
#pragma unroll
    for (int i = 0; i < 4; ++i) {
      int flat = i * 1024 + tid * 4;
      int wr = flat >> 6, wc = flat & 63;
      ushort4 u;
      u.x = f2bf(t[wc + 0][wr]); u.y = f2bf(t[wc + 1][wr]);
      u.z = f2bf(t[wc + 2][wr]); u.w = f2bf(t[wc + 3][wr]);
      *(ushort4*)(Wt + (size_t)(c0 + wr) * EMB + r0 + wc) = u;
    }
  }
}

// ------------- qkv GEMM: 256x256 tile, 8 waves, R7 pipeline (best measured: 213 us) -------------
// [qk | vT] = xb @ Wt^T + bias. col<4096 -> qk[8192][4096] bf16;
// col>=4096 -> vT[b][d][n] via in-LDS transpose. grid 768 x 512 thr.
__global__ __launch_bounds__(512, 2) void gemm_qkv(const u16* __restrict__ Ab,
                                                   const u16* __restrict__ Bb,
                                                   u16* __restrict__ Cb,
                                                   u16* __restrict__ Cb2,
                                                   const float* __restrict__ bias) {
  __shared__ char lds[2][65536];
  constexpr int lda = EMB, ldb = EMB;
  int bid = blockIdx.x;
  int wg = (bid & 7) * 96 + (bid >> 3);            // XCD swizzle
  const u16* A = Ab;
  const u16* Bt = Bb;
  int row0 = (wg / 24) * 256, col0 = (wg % 24) * 256, nk = EMB / 64;

  int tid = threadIdx.x;
  int wave = tid >> 6, lane = tid & 63;
  int wm = wave >> 2, wn = wave & 3;

  int sbase[8];
#pragma unroll
  for (int i = 0; i < 4; ++i) sbase[i] = 32768 + i * 8192 + wave * 1024;
#pragma unroll
  for (int i = 0; i < 4; ++i)
    sbase[4 + i] = i * 4096 + ((wave < 4) ? wave * 1024 : 16384 + (wave - 4) * 1024);

  auto stageb = [&](int bi, int t, int buf) {
    int ob = sbase[bi];
    int obl = ob + lane * 16;
    int row = (obl & 32767) >> 7;
    int cb = obl & 127;
    int c = ((cb ^ ((row & 7) << 4)) >> 1) + t * 64;
    const u16* src = (ob < 32768) ? (A + (size_t)(row0 + row) * lda + c)
                                  : (Bt + (size_t)(col0 + row) * ldb + c);
    GLOAD16(src, (char*)&lds[buf][0] + ob);
  };
  auto ldA = [&](int buf, int rr, int ks) -> bf16x8 {
    int cb = ks * 64 + (lane >> 4) * 16;
    return *(const bf16x8*)&lds[buf][rr * 128 + (cb ^ ((rr & 7) << 4))];
  };
  auto ldB = [&](int buf, int rr, int ks) -> bf16x8 {
    int cb = ks * 64 + (lane >> 4) * 16;
    return *(const bf16x8*)&lds[buf][32768 + rr * 128 + (cb ^ ((rr & 7) << 4))];
  };

  f32x4 acc[8][4];
#pragma unroll
  for (int m = 0; m < 8; ++m)
#pragma unroll
    for (int n = 0; n < 4; ++n) acc[m][n] = (f32x4){0.f, 0.f, 0.f, 0.f};

#pragma unroll
  for (int bi = 0; bi < 8; ++bi) stageb(bi, 0, 0);
#pragma unroll
  for (int bi = 0; bi < 6; ++bi) stageb(bi, 1, 1);
  asm volatile("s_waitcnt vmcnt(6)" ::: "memory");
  __builtin_amdgcn_s_barrier();

  bf16x8 bfg[4][2];
  for (int t = 0; t < nk; ++t) {
    int cur = t & 1, nxt = cur ^ 1;
    bool pf1 = (t + 1 < nk), pf2 = (t + 2 < nk);
    bf16x8 afg[2][2];
    // p0
#pragma unroll
    for (int n = 0; n < 4; ++n)
#pragma unroll
      for (int ks = 0; ks < 2; ++ks)
        bfg[n][ks] = ldB(cur, wn * 64 + n * 16 + (lane & 15), ks);
#pragma unroll
    for (int m = 0; m < 2; ++m)
#pragma unroll
      for (int ks = 0; ks < 2; ++ks)
        afg[m][ks] = ldA(cur, wm * 128 + m * 16 + (lane & 15), ks);
    if (pf1) { stageb(6, t + 1, nxt); stageb(7, t + 1, nxt); }
    __builtin_amdgcn_s_setprio(1);
#pragma unroll
    for (int m = 0; m < 2; ++m)
#pragma unroll
      for (int n = 0; n < 4; ++n)
#pragma unroll
        for (int ks = 0; ks < 2; ++ks)
          acc[m][n] = __builtin_amdgcn_mfma_f32_16x16x32_bf16(
              afg[m][ks], bfg[n][ks], acc[m][n], 0, 0, 0);
    __builtin_amdgcn_s_setprio(0);
    __builtin_amdgcn_s_barrier();
    // p1 (no barrier)
#pragma unroll
    for (int m = 0; m < 2; ++m)
#pragma unroll
      for (int ks = 0; ks < 2; ++ks)
        afg[m][ks] = ldA(cur, wm * 128 + (2 + m) * 16 + (lane & 15), ks);
    if (pf2) { stageb(0, t + 2, cur); stageb(1, t + 2, cur); }
    __builtin_amdgcn_s_setprio(1);
#pragma unroll
    for (int m = 0; m < 2; ++m)
#pragma unroll
      for (int n = 0; n < 4; ++n)
#pragma unroll
        for (int ks = 0; ks < 2; ++ks)
          acc[2 + m][n] = __builtin_amdgcn_mfma_f32_16x16x32_bf16(
              afg[m][ks], bfg[n][ks], acc[2 + m][n], 0, 0, 0);
    __builtin_amdgcn_s_setprio(0);
    // p2
#pragma unroll
    for (int m = 0; m < 2; ++m)
#pragma unroll
      for (int ks = 0; ks < 2; ++ks)
        afg[m][ks] = ldA(cur, wm * 128 + (4 + m) * 16 + (lane & 15), ks);
    if (pf2) { stageb(2, t + 2, cur); stageb(3, t + 2, cur); }
    __builtin_amdgcn_s_setprio(1);
#pragma unroll
    for (int m = 0; m < 2; ++m)
#pragma unroll
      for (int n = 0; n < 4; ++n)
#pragma unroll
        for (int ks = 0; ks < 2; ++ks)
          acc[4 + m][n] = __builtin_amdgcn_mfma_f32_16x16x32_bf16(
              afg[m][ks], bfg[n][ks], acc[4 + m][n], 0, 0, 0);
    __builtin_amdgcn_s_setprio(0);
    __builtin_amdgcn_s_barrier();
    // p3
#pragma unroll
    for (int m = 0; m < 2; ++m)
#pragma unroll
      for (int ks = 0; ks < 2; ++ks)
        afg[m][ks] = ldA(cur, wm * 128 + (6 + m) * 16 + (lane & 15), ks);
    if (pf2) { stageb(4, t + 2, cur); stageb(5, t + 2, cur); }
    __builtin_amdgcn_s_setprio(1);
#pragma unroll
    for (int m = 0; m < 2; ++m)
#pragma unroll
      for (int n = 0; n < 4; ++n)
#pragma unroll
        for (int ks = 0; ks < 2; ++ks)
          acc[6 + m][n] = __builtin_amdgcn_mfma_f32_16x16x32_bf16(
              afg[m][ks], bfg[n][ks], acc[6 + m][n], 0, 0, 0);
    __builtin_amdgcn_s_setprio(0);
    if (pf2)      asm volatile("s_waitcnt vmcnt(6)" ::: "memory");
    else if (pf1) asm volatile("s_waitcnt vmcnt(0)" ::: "memory");
    __builtin_amdgcn_s_barrier();
  }

  int ln = lane & 15;
  int l4 = (lane >> 4) << 2;
  int rb = row0 + wm * 128, cb0 = col0 + wn * 64;
  if (col0 < 4096) {
    u16* C = Cb;
#pragma unroll
    for (int n = 0; n < 4; ++n) {
      float bv = bias[cb0 + n * 16 + ln];
#pragma unroll
      for (int m = 0; m < 8; ++m)
#pragma unroll
        for (int r = 0; r < 4; ++r)
          C[(size_t)(rb + m * 16 + l4 + r) * 4096 + cb0 + n * 16 + ln] =
              f2bf(acc[m][n][r] + bv);
    }
  } else {
    u16* vTb = Cb2 + (size_t)(row0 >> 11) * SEQ * SEQ;
    int nbase = row0 & 2047;
    u16 (*T)[264] = (u16(*)[264])(&lds[0][0]);
    int half = wn >> 1;
    int dloc0 = (wn & 1) * 64;
#pragma unroll
    for (int hh = 0; hh < 2; ++hh) {
      if (half == hh) {
#pragma unroll
        for (int n = 0; n < 4; ++n) {
          float bv = bias[cb0 + n * 16 + ln];
          int dl = dloc0 + n * 16 + ln;
#pragma unroll
          for (int m = 0; m < 8; ++m) {
            int nn = wm * 128 + m * 16 + l4;
#pragma unroll
            for (int r = 0; r < 4; ++r)
              T[dl][nn + r] = f2bf(acc[m][n][r] + bv);
          }
        }
      }
      __syncthreads();
      int dl = tid >> 5, nn = (tid & 31) * 8;
#pragma unroll
      for (int it = 0; it < 8; ++it) {
        int loc = it * 16 + dl;
        *(u16x8v*)&vTb[(size_t)(col0 - 4096 + hh * 128 + loc) * SEQ + nbase + nn] =
            *(const u16x8v*)&T[loc][nn];
      }
      __syncthreads();
    }
  }
}

// ------------- 128x128 NT GEMM, 4 waves, 64KB LDS -> 2 blocks/CU (attention GEMMs) -------------
// MODE 1: att = scale * q @ k^T -> bf16, row stride 4096 u16 (same layout as P). grid 544.
// MODE 2: y = P @ vT^T fp32, K=(qi+1)*128, qi-descending dispatch. grid 1024.
template <int MODE>
__global__ __launch_bounds__(256, 2) void gemm128(const u16* __restrict__ Ab,
                                                  const u16* __restrict__ Bb,
                                                  void* __restrict__ Cb) {
  __shared__ char lds[2][32768];
  constexpr int lda = 4096;
  constexpr int ldb = (MODE == 1) ? 4096 : SEQ;

  int bid = blockIdx.x;
  const u16 *A, *Bt;
  int row0, col0, nk;
  size_t coff;
  if constexpr (MODE == 1) {
    constexpr int CPX = 544 / 8;
    int wg = (bid & 7) * CPX + (bid >> 3);
    int b = wg / 136, tq = wg % 136;
    int qi = (int)((sqrtf(8.f * (float)tq + 1.f) - 1.f) * 0.5f);
    while ((qi + 1) * (qi + 2) / 2 <= tq) ++qi;
    while (qi * (qi + 1) / 2 > tq) --qi;
    int kj = tq - qi * (qi + 1) / 2;
    A = Ab + (size_t)b * SEQ * 4096;       // q slice
    Bt = A + 2048;                         // k slice
    row0 = qi * 128; col0 = kj * 128; nk = EMB / 64;
    coff = (size_t)b * SEQ * 4096;         // att bf16, stride 4096 u16
  } else {
    // qi-descending: heavy blocks dispatched first. 64 blocks per qi (8 per XCD).
    int xcd = bid & 7, idx = bid >> 3;     // idx 0..127
    int qi = 15 - (idx >> 3);
    int g = xcd * 8 + (idx & 7);           // 0..63
    int b = g >> 4, nj = g & 15;
    A = Ab + (size_t)b * SEQ * 4096;       // P, stride 4096
    Bt = Bb + (size_t)b * SEQ * SEQ;       // vT
    row0 = qi * 128; col0 = nj * 128; nk = (qi + 1) * 2;
    coff = (size_t)b * SEQ * SEQ;
  }

  int tid = threadIdx.x;
  int wave = tid >> 6, lane = tid & 63;
  int wm = wave >> 1, wn = wave & 1;       // 2x2 wave grid, 64x64 out each
  int ln = lane & 15;

  int sbase[8];
#pragma unroll
  for (int i = 0; i < 4; ++i) sbase[i] = 16384 + i * 4096 + wave * 1024;
#pragma unroll
  for (int i = 0; i < 4; ++i) sbase[4 + i] = i * 4096 + wave * 1024;

  auto stageb = [&](int bi, int t, int buf) {
    int ob = sbase[bi];
    int obl = ob + lane * 16;
    int row = (obl & 16383) >> 7;
    int cb = obl & 127;
    int c = ((cb ^ ((row & 7) << 4)) >> 1) + t * 64;
    const u16* src = (ob < 16384) ? (A + (size_t)(row0 + row) * lda + c)
                                  : (Bt + (size_t)(col0 + row) * ldb + c);
    GLOAD16(src, (char*)&lds[buf][0] + ob);
  };
  auto ldA = [&](int buf, int rr, int ks) -> bf16x8 {
    int cb = ks * 64 + (lane >> 4) * 16;
    return *(const bf16x8*)&lds[buf][rr * 128 + (cb ^ ((rr & 7) << 4))];
  };
  auto ldB = [&](int buf, int rr, int ks) -> bf16x8 {
    int cb = ks * 64 + (lane >> 4) * 16;
    return *(const bf16x8*)&lds[buf][16384 + rr * 128 + (cb ^ ((rr & 7) << 4))];
  };

  f32x4 acc[4][4];
#pragma unroll
  for (int m = 0; m < 4; ++m)
#pragma unroll
    for (int n = 0; n < 4; ++n) acc[m][n] = (f32x4){0.f, 0.f, 0.f, 0.f};

  // prologue: tile0 fully; tile1 bundles {0,1,2,3,4,6}; vmcnt(6) -> tile0 landed
#pragma unroll
  for (int bi = 0; bi < 8; ++bi) stageb(bi, 0, 0);
  stageb(0, 1, 1); stageb(1, 1, 1); stageb(2, 1, 1); stageb(3, 1, 1);
  stageb(4, 1, 1); stageb(6, 1, 1);
  asm volatile("s_waitcnt vmcnt(6)" ::: "memory");
  __builtin_amdgcn_s_barrier();

  bf16x8 bfg[4][2];
  for (int t = 0; t < nk; ++t) {
    int cur = t & 1, nxt = cur ^ 1;
    bool pf1 = (t + 1 < nk), pf2 = (t + 2 < nk);
    bf16x8 afg[2][2];
    // ---- p0: read B(8) + A m0,m1; stage t+1 {5,7} -> nxt; MFMA; BARRIER ----
#pragma unroll
    for (int n = 0; n < 4; ++n)
#pragma unroll
      for (int ks = 0; ks < 2; ++ks)
        bfg[n][ks] = ldB(cur, wn * 64 + n * 16 + ln, ks);
#pragma unroll
    for (int m = 0; m < 2; ++m)
#pragma unroll
      for (int ks = 0; ks < 2; ++ks)
        afg[m][ks] = ldA(cur, wm * 64 + m * 16 + ln, ks);
    if (pf1) { stageb(5, t + 1, nxt); stageb(7, t + 1, nxt); }
    __builtin_amdgcn_s_setprio(1);
#pragma unroll
    for (int m = 0; m < 2; ++m)
#pragma unroll
      for (int n = 0; n < 4; ++n)
#pragma unroll
        for (int ks = 0; ks < 2; ++ks)
          acc[m][n] = __builtin_amdgcn_mfma_f32_16x16x32_bf16(
              afg[m][ks], bfg[n][ks], acc[m][n], 0, 0, 0);
    __builtin_amdgcn_s_setprio(0);
    __builtin_amdgcn_s_barrier();
    // ---- p1: read A m2,m3; stage t+2 {0..4,6} -> cur; MFMA; vmcnt; BARRIER ----
#pragma unroll
    for (int m = 0; m < 2; ++m)
#pragma unroll
      for (int ks = 0; ks < 2; ++ks)
        afg[m][ks] = ldA(cur, wm * 64 + (2 + m) * 16 + ln, ks);
    if (pf2) {
      stageb(0, t + 2, cur); stageb(1, t + 2, cur); stageb(2, t + 2, cur);
      stageb(3, t + 2, cur); stageb(4, t + 2, cur); stageb(6, t + 2, cur);
    }
    __builtin_amdgcn_s_setprio(1);
#pragma unroll
    for (int m = 0; m < 2; ++m)
#pragma unroll
      for (int n = 0; n < 4; ++n)
#pragma unroll
        for (int ks = 0; ks < 2; ++ks)
          acc[2 + m][n] = __builtin_amdgcn_mfma_f32_16x16x32_bf16(
              afg[m][ks], bfg[n][ks], acc[2 + m][n], 0, 0, 0);
    __builtin_amdgcn_s_setprio(0);
    if (pf2)      asm volatile("s_waitcnt vmcnt(6)" ::: "memory");
    else if (pf1) asm volatile("s_waitcnt vmcnt(0)" ::: "memory");
    __builtin_amdgcn_s_barrier();
  }

  int l4 = (lane >> 4) << 2;
  int rb = row0 + wm * 64, cb0 = col0 + wn * 64;
  if constexpr (MODE == 1) {
    // scaled bf16 att, row stride 4096 u16 (same layout softmax/gemm<2> use)
    u16* C = (u16*)Cb + coff;
    const float scale = 0.022097086912079608f;   // 1/sqrt(2048)
#pragma unroll
    for (int m = 0; m < 4; ++m)
#pragma unroll
      for (int n = 0; n < 4; ++n)
#pragma unroll
        for (int r = 0; r < 4; ++r)
          C[(size_t)(rb + m * 16 + l4 + r) * 4096 + cb0 + n * 16 + ln] =
              f2bf(acc[m][n][r] * scale);
  } else {
    float* C = (float*)Cb + coff;
#pragma unroll
    for (int m = 0; m < 4; ++m)
#pragma unroll
      for (int n = 0; n < 4; ++n)
#pragma unroll
        for (int r = 0; r < 4; ++r)
          C[(size_t)(rb + m * 16 + l4 + r) * SEQ + cb0 + n * 16 + ln] = acc[m][n][r];
  }
}

// ---------------- row softmax: att bf16 -> P bf16 (in place, stride 4096), denom ----------------
// 256 threads x 8 contiguous els (one ushort8 load/store). 128-granular extent; masked exp->0.
__global__ __launch_bounds__(256) void softmax_kern(u16* __restrict__ att,
                                                    float* __restrict__ denom) {
  int row = blockIdx.x;          // b*SEQ + q
  int q = row & (SEQ - 1);
  u16* arow = att + (size_t)row * 4096;
  int jlen = ((q >> 7) + 1) << 7;          // 128-tile-aligned row extent
  int tid = threadIdx.x;
  int j0 = tid * 8;
  float NI = -__builtin_inff();
  float a[8];
#pragma unroll
  for (int e = 0; e < 8; ++e) a[e] = NI;
  if (j0 < jlen) {
    u16x8v v = *(const u16x8v*)(arow + j0);
#pragma unroll
    for (int e = 0; e < 8; ++e)
      a[e] = (j0 + e <= q) ? bf2f(v[e]) : NI;
  }
  float mx = a[0];
#pragma unroll
  for (int e = 1; e < 8; ++e) mx = fmaxf(mx, a[e]);
#pragma unroll
  for (int off = 32; off; off >>= 1) mx = fmaxf(mx, __shfl_xor(mx, off, 64));
  __shared__ float red[8];
  int wv = tid >> 6;
  if ((tid & 63) == 0) red[wv] = mx;
  __syncthreads();
  mx = fmaxf(fmaxf(red[0], red[1]), fmaxf(red[2], red[3]));
  float s = 0.f;
#pragma unroll
  for (int e = 0; e < 8; ++e) { a[e] = expf(a[e] - mx); s += a[e]; }
#pragma unroll
  for (int off = 32; off; off >>= 1) s += __shfl_xor(s, off, 64);
  if ((tid & 63) == 0) red[4 + wv] = s;
  __syncthreads();                          // fences all arow reads before P writes
  s = red[4] + red[5] + red[6] + red[7];
  float inv = 1.0f / s;
  if (j0 < jlen) {
    u16x8v u;
#pragma unroll
    for (int e = 0; e < 8; ++e) u[e] = f2bf(a[e] * inv);
    *(u16x8v*)(arow + j0) = u;
  }
  if (tid == 0) denom[row] = s;
}

extern "C" void kernel_launch(void* const* d_in, const int* in_sizes, int n_in,
                              void* d_out, int out_size, void* d_ws, size_t ws_size,
                              hipStream_t stream) {
  const float* x    = (const float*)d_in[0];
  const float* W    = (const float*)d_in[1];
  const float* bias = (const float*)d_in[2];

  // ws layout (201,326,592 B):
  //  [0,         67108864)  qk bf16 [8192][4096] (q cols 0..2047, k cols 2048..4095)
  //  [67108864, 100663296)  vT bf16 [4][2048][2048]   (written by gemm_qkv epilogue)
  //  [100663296,134217728)  xb bf16 [8192][2048]      (dead after gemm_qkv)
  //  [134217728,201326592)  phase1: Wt bf16 (first 25MB, dead after gemm_qkv)
  //                         phase2: att bf16 / P bf16 in-place [8192 rows][4096 u16]
  if (ws_size < 201326592u) return;

  char* w = (char*)d_ws;
  u16*   qk  = (u16*)w;
  u16*   vT  = (u16*)(w + 67108864);
  u16*   xb  = (u16*)(w + 100663296);
  u16*   Wt  = (u16*)(w + 134217728);
  u16*   att = (u16*)(w + 134217728);      // bf16, row stride 4096 u16; P in place

  float* y     = (float*)d_out;
  float* denom = y + (size_t)4 * SEQ * SEQ;

  prep_kern<<<19456, 256, 0, stream>>>(x, xb, W, Wt);
  gemm_qkv<<<768, 512, 0, stream>>>(xb, Wt, qk, vT, bias);
  gemm128<1><<<544, 256, 0, stream>>>(qk, nullptr, att);
  softmax_kern<<<8192, 256, 0, stream>>>(att, denom);
  gemm128<2><<<1024, 256, 0, stream>>>(att, vT, y);
}